// Round 12
// baseline (128.649 us; speedup 1.0000x reference)
//
#include <hip/hip_runtime.h>
#include <math.h>

// Problem constants
#define Bn   4
#define Cc   64
#define Hh   128
#define Ww   128
#define Oo   64
#define HW   16384
#define NPAR 27

// Workspace layout (float offsets)
#define WB2_OFF 0        // bf16 AT2[t][cc][mt2][lane64][8] = 36864 shorts
#define WB_OFF  18432    // bf16 ATd[t][h][mt4][lane64][8]  = 36864 shorts

typedef __attribute__((ext_vector_type(8))) short bf16x8;
typedef __attribute__((ext_vector_type(4))) short s16x4;
typedef __attribute__((ext_vector_type(4))) float f32x4;
typedef __attribute__((ext_vector_type(2), aligned(4))) float f32x2u;

__device__ __forceinline__ short f2bf(float f) {
    unsigned u = __builtin_bit_cast(unsigned, f);
    u += 0x7FFFu + ((u >> 16) & 1u);        // RNE
    return (short)(u >> 16);
}

// ---------------------------------------------------------------------------
// prep: pre-transpose weights into MFMA A-fragment order (unchanged from r4).
// ---------------------------------------------------------------------------
__global__ void prep_weights(const float* __restrict__ w_off,
                             const float* __restrict__ w_mod,
                             const float* __restrict__ w_reg,
                             float* __restrict__ ws) {
    int i = blockIdx.x * 256 + threadIdx.x;
    short* at2 = (short*)(ws + WB2_OFF);
    short* atd = (short*)(ws + WB_OFF);
    if (i < 36864) {
        int j = i & 7, l = (i >> 3) & 63, mt = (i >> 9) & 1, cc = (i >> 10) & 3, t = i >> 12;
        int lm = l & 15, quad = l >> 4;
        int row = mt * 16 + lm;
        int c = cc * 32 + quad * 8 + j;
        float v = 0.f;
        if (row < 18)      v = w_off[row * 1152 + c * 9 + t];
        else if (row < 27) v = w_mod[(row - 18) * 1152 + c * 9 + t];
        at2[i] = f2bf(v);
    } else if (i < 73728) {
        int e = i - 36864;
        int j = e & 7, l = (e >> 3) & 63, mt = (e >> 9) & 3, h = (e >> 11) & 1, t = e >> 12;
        int lm = l & 15, quad = l >> 4;
        int o = mt * 16 + lm;
        int c = h * 32 + quad * 8 + j;
        atd[e] = f2bf(w_reg[o * 576 + c * 9 + t]);
    }
}

// ---------------------------------------------------------------------------
// FUSED kernel round 12 = r11 + par-via-__shfl (no LDS round trip).
// r11 clean: FETCH 124->18MB (swizzle), fused 53.6us, VGPR 52, WRITE=16384.
// Remaining: latency-gapped (VALU 33/Mfma 6.7/HBM 8/Occ 33, issue-work
// ~8k cy/block vs 32k wall), TLP capped at 16 waves/CU by grid. Chain cut:
// each tap read its 3 params from LDS (~120cy link) -- but they were
// computed IN REGISTERS by the same wave (lane (quad,lm) holds j for pixel
// (w,lm); param j of pixel (w,lm) sits at lane ((j>>2)&3)*16+lm). Replace
// parL write + 3 ds_read_b32/tap with 3 __shfl/tap (reg-to-reg, ~4cy).
// parL (7.4KB) freed -> deform window back to DROWS=10 (fewer fallback
// lanes than r10's 8-row diet). tr[8] stays live (+8 reg, 52->~60 <= 64).
// ---------------------------------------------------------------------------
#define CPSTR 136    // bf16 per conv pos: 128 ch + 8 pad
#define DPSTR 36     // f32 per deform pos: 32 ch + 4 pad
#define DROWS 10     // deform window rows

struct TapP {
    float wa0, wb0, wa1, wb1;
    int ia, ib, gx0, gx1;
    bool in;
};

__device__ __forceinline__ TapP tap_params_v(float py, float px, float m,
                                             int rb, int cb) {
    float fy = floorf(py), fx = floorf(px);
    int y0 = (int)fy, x0 = (int)fx;
    int y1 = y0 + 1;
    float wy1 = py - fy, wx1 = px - fx;
    float wy0 = 1.f - wy1, wx0 = 1.f - wx1;
    bool vy0 = (unsigned)y0 < 128u, vy1 = (unsigned)y1 < 128u;
    bool vx0 = (unsigned)x0 < 128u, vx1 = (unsigned)(x0 + 1) < 128u;
    int cy0 = min(max(y0, 0), 127), cy1 = min(max(y1, 0), 127);
    int bx2 = min(max(x0, 0), 126);
    bool sel_lo = (x0 < 0), sel_hi = (x0 > 126);
    float w00 = (vy0 && vx0) ? wy0 * wx0 * m : 0.f;
    float w01 = (vy0 && vx1) ? wy0 * wx1 * m : 0.f;
    float w10 = (vy1 && vx0) ? wy1 * wx0 * m : 0.f;
    float w11 = (vy1 && vx1) ? wy1 * wx1 * m : 0.f;
    TapP r;
    // fold boundary handling into pair weights: wa->[bx2], wb->[bx2+1]
    r.wa0 = sel_lo ? w01 : (sel_hi ? 0.f : w00);
    r.wb0 = sel_hi ? w00 : (sel_lo ? 0.f : w01);
    r.wa1 = sel_lo ? w11 : (sel_hi ? 0.f : w10);
    r.wb1 = sel_hi ? w10 : (sel_lo ? 0.f : w11);
    int ty0 = cy0 - rb, ty1 = cy1 - rb, tx = bx2 - cb;
    r.ia = ty0 * 24 + tx;
    r.ib = ty1 * 24 + tx;
    r.gx0 = (cy0 << 7) + bx2;
    r.gx1 = (cy1 << 7) + bx2;
    r.in = ((unsigned)ty0 <= (unsigned)(DROWS - 1)) &&
           ((unsigned)ty1 <= (unsigned)(DROWS - 1)) &&
           ((unsigned)tx <= 22u);
    return r;
}

__global__ __launch_bounds__(256, 4)
void fused_dcn(const float* __restrict__ x, const float* __restrict__ g,
               const float* __restrict__ ws_,
               const float* __restrict__ b_off, const float* __restrict__ b_mod,
               float* __restrict__ out) {
    __shared__ __align__(16) char Ubuf[144 * CPSTR * 2];  // 39168 B, unioned
    short* Wd = (short*)Ubuf;                  // conv window [144 pos][136]
    float* Xw = (float*)Ubuf;                  // deform window [240 pos][36]

    const int tid = threadIdx.x;
    const int l = tid & 63, lm = l & 15, quad = l >> 4;
    const int w = __builtin_amdgcn_readfirstlane(tid >> 6);   // wave = pixel row

    // XCD-aware swizzle: XCD k owns tiles [k*128,(k+1)*128) = half an image.
    const int bid = ((blockIdx.z << 5) + blockIdx.y) * 8 + blockIdx.x;  // grid (8,32,4)
    const int swz = ((bid & 7) << 7) | (bid >> 3);                      // bijective, 1024
    const int tx_ = swz & 7, ty_ = (swz >> 3) & 31, b = swz >> 8;
    const int ho0 = ty_ * 4, wo0 = tx_ * 16;

    const short* at2 = (const short*)(ws_ + WB2_OFF);
    const short* atd = (const short*)(ws_ + WB_OFF);
    const float* xb = x + ((size_t)(b * Cc) << 14);
    const float* gb = g + ((size_t)(b * Cc) << 14);

    // ===================== conv phase (r4 structure) =======================
    {
        const int row_base = ho0 - 1;     // may be -1: halo rows zero-filled
        const int col_base = wo0 - 4;     // 4-aligned; halo cols zero-filled
        for (int s = tid; s < 1152; s += 256) {
            int pq = s >> 5, cq = s & 31;
            int r = pq / 6, c4 = (pq - r * 6) * 4;
            int row = row_base + r, col = col_base + c4;
            bool ok = ((unsigned)row < 128u) && ((unsigned)col < 128u);
            f32x4 v0, v1, v2, v3;
            {
                int ch = cq * 4;
                const float* p0 = (ch < Cc) ? (xb + ((size_t)ch << 14)) : (gb + ((size_t)(ch - Cc) << 14));
                const float* p1 = (ch + 1 < Cc) ? (xb + ((size_t)(ch + 1) << 14)) : (gb + ((size_t)(ch + 1 - Cc) << 14));
                const float* p2 = (ch + 2 < Cc) ? (xb + ((size_t)(ch + 2) << 14)) : (gb + ((size_t)(ch + 2 - Cc) << 14));
                const float* p3 = (ch + 3 < Cc) ? (xb + ((size_t)(ch + 3) << 14)) : (gb + ((size_t)(ch + 3 - Cc) << 14));
                f32x4 zz = {0.f, 0.f, 0.f, 0.f};
                size_t off = ((size_t)(row << 7) + col);
                v0 = ok ? *(const f32x4*)(p0 + off) : zz;
                v1 = ok ? *(const f32x4*)(p1 + off) : zz;
                v2 = ok ? *(const f32x4*)(p2 + off) : zz;
                v3 = ok ? *(const f32x4*)(p3 + off) : zz;
            }
#pragma unroll
            for (int p = 0; p < 4; p++) {
                s16x4 o4 = { f2bf(v0[p]), f2bf(v1[p]), f2bf(v2[p]), f2bf(v3[p]) };
                *(s16x4*)&Wd[(r * 24 + c4 + p) * CPSTR + cq * 4] = o4;
            }
        }
    }
    __syncthreads();

    f32x4 acc0 = {0.f, 0.f, 0.f, 0.f}, acc1 = {0.f, 0.f, 0.f, 0.f};
#pragma unroll
    for (int t = 0; t < 9; t++) {
        int dy = t / 3, dx = t - dy * 3;
        int pos = (w + dy) * 24 + (lm + dx + 3);
#pragma unroll
        for (int cc = 0; cc < 4; cc++) {
            bf16x8 bfr = *(const bf16x8*)&Wd[pos * CPSTR + cc * 32 + quad * 8];
            bf16x8 a0 = *(const bf16x8*)(at2 + t * 4096 + cc * 1024 + l * 8);
            bf16x8 a1 = *(const bf16x8*)(at2 + t * 4096 + cc * 1024 + 512 + l * 8);
            acc0 = __builtin_amdgcn_mfma_f32_16x16x32_bf16(a0, bfr, acc0, 0, 0, 0);
            acc1 = __builtin_amdgcn_mfma_f32_16x16x32_bf16(a1, bfr, acc1, 0, 0, 0);
        }
    }

    // -------- transforms (bias/coords/sigmoid) in registers ---------------
    // lane (quad,lm) holds j = mt*16 + quad*4 + reg for pixel (ho0+w, wo0+lm)
    const int ho = ho0 + w, wo = wo0 + lm;
    float tr[8];
#pragma unroll
    for (int mt = 0; mt < 2; mt++) {
        f32x4 a = mt ? acc1 : acc0;
#pragma unroll
        for (int reg = 0; reg < 4; reg++) {
            int j = mt * 16 + quad * 4 + reg;
            float v = a[reg];
            float r = 0.f;
            if (j < 18) {
                int k = j >> 1;
                float vb = v + b_off[j];
                r = (j & 1) ? (vb + (float)(k - (k / 3) * 3 + wo - 1))
                            : (vb + (float)(k / 3 + ho - 1));
            } else if (j < 27) {
                int k = j - 18;
                r = 2.f / (1.f + __expf(-(v + b_mod[k])));
            }
            tr[mt * 4 + reg] = r;
        }
    }

    __syncthreads();   // all waves done reading Wd -> Xw may overwrite

    // ===================== deform phase ====================================
    const int rb = min(max(ho0 - 3, 0), 128 - DROWS);
    const int cb = min(max(wo0 - 4, 0), 128 - 24);    // 4-aligned

    auto STAGE = [&](int h) {
        for (int s = tid; s < DROWS * 6 * 8; s += 256) {
            int pq = s >> 3, cq = s & 7;
            int r = pq / 6, c4 = (pq - r * 6) * 4;
            size_t off = (size_t)((rb + r) << 7) + cb + c4;
            f32x4 v0 = *(const f32x4*)(xb + ((size_t)(h * 32 + cq * 4 + 0) << 14) + off);
            f32x4 v1 = *(const f32x4*)(xb + ((size_t)(h * 32 + cq * 4 + 1) << 14) + off);
            f32x4 v2 = *(const f32x4*)(xb + ((size_t)(h * 32 + cq * 4 + 2) << 14) + off);
            f32x4 v3 = *(const f32x4*)(xb + ((size_t)(h * 32 + cq * 4 + 3) << 14) + off);
#pragma unroll
            for (int p = 0; p < 4; p++) {
                f32x4 o4 = { v0[p], v1[p], v2[p], v3[p] };
                *(f32x4*)&Xw[(r * 24 + c4 + p) * DPSTR + cq * 4] = o4;
            }
        }
    };

    STAGE(0);
    __syncthreads();

    f32x4 acc[4];
#pragma unroll
    for (int mt = 0; mt < 4; mt++) acc[mt] = (f32x4){0.f, 0.f, 0.f, 0.f};

    auto T_LOOP = [&](int h) {
#pragma unroll
        for (int t = 0; t < 9; t++) {
            // params via cross-lane shuffle: param j of pixel (w,lm) lives at
            // lane ((j>>2)&3)*16+lm, slot (j>>4)*4+(j&3). All indices literal.
            const int jy = 2 * t, jx = 2 * t + 1, jm = 18 + t;
            float py = __shfl(tr[(jy >> 4) * 4 + (jy & 3)], ((jy >> 2) & 3) * 16 + lm);
            float px = __shfl(tr[(jx >> 4) * 4 + (jx & 3)], ((jx >> 2) & 3) * 16 + lm);
            float m  = __shfl(tr[(jm >> 4) * 4 + (jm & 3)], ((jm >> 2) & 3) * 16 + lm);
            TapP P = tap_params_v(py, px, m, rb, cb);
            int ia = min(max(P.ia, 0), DROWS * 24 - 2);
            int ib = min(max(P.ib, 0), DROWS * 24 - 2);
            union { short s8[8]; bf16x8 v; } u;
#pragma unroll
            for (int hf = 0; hf < 2; hf++) {
                const float* pa = Xw + ia * DPSTR + quad * 8 + hf * 4;
                const float* pb = Xw + ib * DPSTR + quad * 8 + hf * 4;
                f32x4 c0 = *(const f32x4*)(pa);
                f32x4 c1 = *(const f32x4*)(pa + DPSTR);
                f32x4 c2 = *(const f32x4*)(pb);
                f32x4 c3 = *(const f32x4*)(pb + DPSTR);
                if (__builtin_expect(!P.in, 0)) {   // rare per-lane patch
#pragma unroll
                    for (int j = 0; j < 4; j++) {
                        int cch = h * 32 + quad * 8 + hf * 4 + j;
                        const float* xc = xb + ((size_t)cch << 14);
                        f32x2u q0 = *(const f32x2u*)(xc + P.gx0);
                        f32x2u q1 = *(const f32x2u*)(xc + P.gx1);
                        c0[j] = q0.x; c1[j] = q0.y; c2[j] = q1.x; c3[j] = q1.y;
                    }
                }
#pragma unroll
                for (int j = 0; j < 4; j++)
                    u.s8[hf * 4 + j] = f2bf(P.wa0 * c0[j] + P.wb0 * c1[j] +
                                            P.wa1 * c2[j] + P.wb1 * c3[j]);
            }
#pragma unroll
            for (int mt = 0; mt < 4; mt++) {
                bf16x8 a = *(const bf16x8*)(atd + t * 4096 + h * 2048 + mt * 512 + l * 8);
                acc[mt] = __builtin_amdgcn_mfma_f32_16x16x32_bf16(a, u.v, acc[mt], 0, 0, 0);
            }
        }
    };

    T_LOOP(0);
    __syncthreads();      // all waves done reading half-0 window
    STAGE(1);
    __syncthreads();
    T_LOOP(1);

    // Epilogue: D[row=quad*4+reg][col=lm]; o = mt*16+row, pixel = (ho, wo)
#pragma unroll
    for (int mt = 0; mt < 4; mt++) {
        float* op = out + ((size_t)(b * Oo + mt * 16 + quad * 4) << 14) + (ho << 7) + wo;
#pragma unroll
        for (int reg = 0; reg < 4; reg++)
            op[(size_t)reg << 14] = acc[mt][reg];
    }
}

// ---------------------------------------------------------------------------
extern "C" void kernel_launch(void* const* d_in, const int* in_sizes, int n_in,
                              void* d_out, int out_size, void* d_ws, size_t ws_size,
                              hipStream_t stream) {
    const float* x     = (const float*)d_in[0];
    const float* guide = (const float*)d_in[1];
    const float* w_off = (const float*)d_in[2];
    const float* b_off = (const float*)d_in[3];
    const float* w_mod = (const float*)d_in[4];
    const float* b_mod = (const float*)d_in[5];
    const float* w_reg = (const float*)d_in[6];
    float* out = (float*)d_out;
    float* ws  = (float*)d_ws;

    hipLaunchKernelGGL(prep_weights, dim3((73728 + 255) / 256), dim3(256),
                       0, stream, w_off, w_mod, w_reg, ws);
    hipLaunchKernelGGL(fused_dcn, dim3(Ww / 16, Hh / 4, Bn), dim3(256),
                       0, stream, x, guide, ws, b_off, b_mod, out);
}

// Round 13
// 128.543 us; speedup vs baseline: 1.0008x; 1.0008x over previous
//
#include <hip/hip_runtime.h>
#include <math.h>

// Problem constants
#define Bn   4
#define Cc   64
#define Hh   128
#define Ww   128
#define Oo   64
#define HW   16384
#define NPAR 27

// Workspace layout (float offsets)
#define WB2_OFF 0        // bf16 AT2[t][cc][mt2][lane64][8] = 36864 shorts
#define WB_OFF  18432    // bf16 ATd[t][h][mt4][lane64][8]  = 36864 shorts

typedef __attribute__((ext_vector_type(8))) short bf16x8;
typedef __attribute__((ext_vector_type(4))) short s16x4;
typedef __attribute__((ext_vector_type(4))) float f32x4;
typedef __attribute__((ext_vector_type(2), aligned(4))) float f32x2u;

__device__ __forceinline__ short f2bf(float f) {
    unsigned u = __builtin_bit_cast(unsigned, f);
    u += 0x7FFFu + ((u >> 16) & 1u);        // RNE
    return (short)(u >> 16);
}
__device__ __forceinline__ short f2h(float f) {        // f32 -> fp16 (RNE)
    return __builtin_bit_cast(short, (_Float16)f);
}
__device__ __forceinline__ float h2f(short s) {        // fp16 -> f32 (exact)
    return (float)__builtin_bit_cast(_Float16, s);
}

// ---------------------------------------------------------------------------
// prep: pre-transpose weights into MFMA A-fragment order (unchanged from r4).
// ---------------------------------------------------------------------------
__global__ void prep_weights(const float* __restrict__ w_off,
                             const float* __restrict__ w_mod,
                             const float* __restrict__ w_reg,
                             float* __restrict__ ws) {
    int i = blockIdx.x * 256 + threadIdx.x;
    short* at2 = (short*)(ws + WB2_OFF);
    short* atd = (short*)(ws + WB_OFF);
    if (i < 36864) {
        int j = i & 7, l = (i >> 3) & 63, mt = (i >> 9) & 1, cc = (i >> 10) & 3, t = i >> 12;
        int lm = l & 15, quad = l >> 4;
        int row = mt * 16 + lm;
        int c = cc * 32 + quad * 8 + j;
        float v = 0.f;
        if (row < 18)      v = w_off[row * 1152 + c * 9 + t];
        else if (row < 27) v = w_mod[(row - 18) * 1152 + c * 9 + t];
        at2[i] = f2bf(v);
    } else if (i < 73728) {
        int e = i - 36864;
        int j = e & 7, l = (e >> 3) & 63, mt = (e >> 9) & 3, h = (e >> 11) & 1, t = e >> 12;
        int lm = l & 15, quad = l >> 4;
        int o = mt * 16 + lm;
        int c = h * 32 + quad * 8 + j;
        atd[e] = f2bf(w_reg[o * 576 + c * 9 + t]);
    }
}

// ---------------------------------------------------------------------------
// FUSED kernel round 13 = r12 + fp16 deform window, single-stage.
// r12 counters (fused 55us, VALU 33/Mfma 6.7/HBM 8): the deform per-tap cost
// is 16 ds_read_b128 (f32 corners, 2 halves x 2 hf x 4) + tap_params twice
// (once per c-half) + 3 barriers for f32 half-restaging -- all because only
// 32 f32 channels fit in LDS. fp16 window fits ALL 64 ch (240pos x 72 x 2B
// = 34.6KB <= 39.2KB conv union): ONE stage, 3 barriers total, tap_params
// once/tap, corner reads ds_read_b64 (half the LDS-pipe cycles), cvt via
// native v_cvt_f32_f16. Numerics: f16 corner error (2^-11 rel) is ~8x below
// the EXISTING bf16 blend error (2^-8) that dominates absmax=0.0156 ->
// expected absmax <= ~0.018. Fallback lanes recompute from f32 global
// (unchanged math). Params stay in tr[] via __shfl (parL would push LDS to
// 41.5KB -> 3 blocks/CU).
// ---------------------------------------------------------------------------
#define CPSTR 136    // bf16 per conv pos: 128 ch + 8 pad
#define XSTR  72     // f16 per deform pos: 64 ch + 8 pad (144B)
#define DROWS 10     // deform window rows

struct TapP {
    float wa0, wb0, wa1, wb1;
    int ia, ib, gx0, gx1;
    bool in;
};

__device__ __forceinline__ TapP tap_params_v(float py, float px, float m,
                                             int rb, int cb) {
    float fy = floorf(py), fx = floorf(px);
    int y0 = (int)fy, x0 = (int)fx;
    int y1 = y0 + 1;
    float wy1 = py - fy, wx1 = px - fx;
    float wy0 = 1.f - wy1, wx0 = 1.f - wx1;
    bool vy0 = (unsigned)y0 < 128u, vy1 = (unsigned)y1 < 128u;
    bool vx0 = (unsigned)x0 < 128u, vx1 = (unsigned)(x0 + 1) < 128u;
    int cy0 = min(max(y0, 0), 127), cy1 = min(max(y1, 0), 127);
    int bx2 = min(max(x0, 0), 126);
    bool sel_lo = (x0 < 0), sel_hi = (x0 > 126);
    float w00 = (vy0 && vx0) ? wy0 * wx0 * m : 0.f;
    float w01 = (vy0 && vx1) ? wy0 * wx1 * m : 0.f;
    float w10 = (vy1 && vx0) ? wy1 * wx0 * m : 0.f;
    float w11 = (vy1 && vx1) ? wy1 * wx1 * m : 0.f;
    TapP r;
    // fold boundary handling into pair weights: wa->[bx2], wb->[bx2+1]
    r.wa0 = sel_lo ? w01 : (sel_hi ? 0.f : w00);
    r.wb0 = sel_hi ? w00 : (sel_lo ? 0.f : w01);
    r.wa1 = sel_lo ? w11 : (sel_hi ? 0.f : w10);
    r.wb1 = sel_hi ? w10 : (sel_lo ? 0.f : w11);
    int ty0 = cy0 - rb, ty1 = cy1 - rb, tx = bx2 - cb;
    r.ia = ty0 * 24 + tx;
    r.ib = ty1 * 24 + tx;
    r.gx0 = (cy0 << 7) + bx2;
    r.gx1 = (cy1 << 7) + bx2;
    r.in = ((unsigned)ty0 <= (unsigned)(DROWS - 1)) &&
           ((unsigned)ty1 <= (unsigned)(DROWS - 1)) &&
           ((unsigned)tx <= 22u);
    return r;
}

__global__ __launch_bounds__(256, 4)
void fused_dcn(const float* __restrict__ x, const float* __restrict__ g,
               const float* __restrict__ ws_,
               const float* __restrict__ b_off, const float* __restrict__ b_mod,
               float* __restrict__ out) {
    __shared__ __align__(16) char Ubuf[144 * CPSTR * 2];  // 39168 B, unioned
    short* Wd = (short*)Ubuf;                  // conv window [144 pos][136]
    short* Xh = (short*)Ubuf;                  // deform window [240 pos][72] f16

    const int tid = threadIdx.x;
    const int l = tid & 63, lm = l & 15, quad = l >> 4;
    const int w = __builtin_amdgcn_readfirstlane(tid >> 6);   // wave = pixel row

    // XCD-aware swizzle: XCD k owns tiles [k*128,(k+1)*128) = half an image.
    const int bid = ((blockIdx.z << 5) + blockIdx.y) * 8 + blockIdx.x;  // grid (8,32,4)
    const int swz = ((bid & 7) << 7) | (bid >> 3);                      // bijective, 1024
    const int tx_ = swz & 7, ty_ = (swz >> 3) & 31, b = swz >> 8;
    const int ho0 = ty_ * 4, wo0 = tx_ * 16;

    const short* at2 = (const short*)(ws_ + WB2_OFF);
    const short* atd = (const short*)(ws_ + WB_OFF);
    const float* xb = x + ((size_t)(b * Cc) << 14);
    const float* gb = g + ((size_t)(b * Cc) << 14);

    // ===================== conv phase (r4 structure) =======================
    {
        const int row_base = ho0 - 1;     // may be -1: halo rows zero-filled
        const int col_base = wo0 - 4;     // 4-aligned; halo cols zero-filled
        for (int s = tid; s < 1152; s += 256) {
            int pq = s >> 5, cq = s & 31;
            int r = pq / 6, c4 = (pq - r * 6) * 4;
            int row = row_base + r, col = col_base + c4;
            bool ok = ((unsigned)row < 128u) && ((unsigned)col < 128u);
            f32x4 v0, v1, v2, v3;
            {
                int ch = cq * 4;
                const float* p0 = (ch < Cc) ? (xb + ((size_t)ch << 14)) : (gb + ((size_t)(ch - Cc) << 14));
                const float* p1 = (ch + 1 < Cc) ? (xb + ((size_t)(ch + 1) << 14)) : (gb + ((size_t)(ch + 1 - Cc) << 14));
                const float* p2 = (ch + 2 < Cc) ? (xb + ((size_t)(ch + 2) << 14)) : (gb + ((size_t)(ch + 2 - Cc) << 14));
                const float* p3 = (ch + 3 < Cc) ? (xb + ((size_t)(ch + 3) << 14)) : (gb + ((size_t)(ch + 3 - Cc) << 14));
                f32x4 zz = {0.f, 0.f, 0.f, 0.f};
                size_t off = ((size_t)(row << 7) + col);
                v0 = ok ? *(const f32x4*)(p0 + off) : zz;
                v1 = ok ? *(const f32x4*)(p1 + off) : zz;
                v2 = ok ? *(const f32x4*)(p2 + off) : zz;
                v3 = ok ? *(const f32x4*)(p3 + off) : zz;
            }
#pragma unroll
            for (int p = 0; p < 4; p++) {
                s16x4 o4 = { f2bf(v0[p]), f2bf(v1[p]), f2bf(v2[p]), f2bf(v3[p]) };
                *(s16x4*)&Wd[(r * 24 + c4 + p) * CPSTR + cq * 4] = o4;
            }
        }
    }
    __syncthreads();

    f32x4 acc0 = {0.f, 0.f, 0.f, 0.f}, acc1 = {0.f, 0.f, 0.f, 0.f};
#pragma unroll
    for (int t = 0; t < 9; t++) {
        int dy = t / 3, dx = t - dy * 3;
        int pos = (w + dy) * 24 + (lm + dx + 3);
#pragma unroll
        for (int cc = 0; cc < 4; cc++) {
            bf16x8 bfr = *(const bf16x8*)&Wd[pos * CPSTR + cc * 32 + quad * 8];
            bf16x8 a0 = *(const bf16x8*)(at2 + t * 4096 + cc * 1024 + l * 8);
            bf16x8 a1 = *(const bf16x8*)(at2 + t * 4096 + cc * 1024 + 512 + l * 8);
            acc0 = __builtin_amdgcn_mfma_f32_16x16x32_bf16(a0, bfr, acc0, 0, 0, 0);
            acc1 = __builtin_amdgcn_mfma_f32_16x16x32_bf16(a1, bfr, acc1, 0, 0, 0);
        }
    }

    // -------- transforms (bias/coords/sigmoid) in registers ---------------
    // lane (quad,lm) holds j = mt*16 + quad*4 + reg for pixel (ho0+w, wo0+lm)
    const int ho = ho0 + w, wo = wo0 + lm;
    float tr[8];
#pragma unroll
    for (int mt = 0; mt < 2; mt++) {
        f32x4 a = mt ? acc1 : acc0;
#pragma unroll
        for (int reg = 0; reg < 4; reg++) {
            int j = mt * 16 + quad * 4 + reg;
            float v = a[reg];
            float r = 0.f;
            if (j < 18) {
                int k = j >> 1;
                float vb = v + b_off[j];
                r = (j & 1) ? (vb + (float)(k - (k / 3) * 3 + wo - 1))
                            : (vb + (float)(k / 3 + ho - 1));
            } else if (j < 27) {
                int k = j - 18;
                r = 2.f / (1.f + __expf(-(v + b_mod[k])));
            }
            tr[mt * 4 + reg] = r;
        }
    }

    __syncthreads();   // all waves done reading Wd -> Xh may overwrite

    // ===================== deform phase ====================================
    const int rb = min(max(ho0 - 3, 0), 128 - DROWS);
    const int cb = min(max(wo0 - 4, 0), 128 - 24);    // 4-aligned

    // ONE stage: all 64 ch as fp16 ch-inner [pos][72]. 960 tasks: 4 f32x4
    // global loads (4ch x 4cols), cvt f16, transpose, 4 ds_write_b64.
    for (int s = tid; s < 960; s += 256) {
        int pq = s >> 4, cq = s & 15;
        int r = pq / 6, c4 = (pq - r * 6) * 4;
        size_t off = (size_t)((rb + r) << 7) + cb + c4;
        f32x4 v0 = *(const f32x4*)(xb + ((size_t)(cq * 4 + 0) << 14) + off);
        f32x4 v1 = *(const f32x4*)(xb + ((size_t)(cq * 4 + 1) << 14) + off);
        f32x4 v2 = *(const f32x4*)(xb + ((size_t)(cq * 4 + 2) << 14) + off);
        f32x4 v3 = *(const f32x4*)(xb + ((size_t)(cq * 4 + 3) << 14) + off);
#pragma unroll
        for (int p = 0; p < 4; p++) {
            s16x4 o4 = { f2h(v0[p]), f2h(v1[p]), f2h(v2[p]), f2h(v3[p]) };
            *(s16x4*)&Xh[(r * 24 + c4 + p) * XSTR + cq * 4] = o4;
        }
    }
    __syncthreads();

    f32x4 acc[4];
#pragma unroll
    for (int mt = 0; mt < 4; mt++) acc[mt] = (f32x4){0.f, 0.f, 0.f, 0.f};

    // Single T_LOOP: 9 taps, h inner; tap_params ONCE per tap; no barriers.
#pragma unroll
    for (int t = 0; t < 9; t++) {
        const int jy = 2 * t, jx = 2 * t + 1, jm = 18 + t;
        float py = __shfl(tr[(jy >> 4) * 4 + (jy & 3)], ((jy >> 2) & 3) * 16 + lm);
        float px = __shfl(tr[(jx >> 4) * 4 + (jx & 3)], ((jx >> 2) & 3) * 16 + lm);
        float m  = __shfl(tr[(jm >> 4) * 4 + (jm & 3)], ((jm >> 2) & 3) * 16 + lm);
        TapP P = tap_params_v(py, px, m, rb, cb);
        int ia = min(max(P.ia, 0), DROWS * 24 - 2);
        int ib = min(max(P.ib, 0), DROWS * 24 - 2);
#pragma unroll
        for (int h = 0; h < 2; h++) {
            union { short s8[8]; bf16x8 v; } u;
#pragma unroll
            for (int hf = 0; hf < 2; hf++) {
                const short* pa = Xh + ia * XSTR + h * 32 + quad * 8 + hf * 4;
                const short* pb = Xh + ib * XSTR + h * 32 + quad * 8 + hf * 4;
                s16x4 A0 = *(const s16x4*)(pa);          // (y0, x)   4 ch f16
                s16x4 A1 = *(const s16x4*)(pa + XSTR);   // (y0, x+1)
                s16x4 B0 = *(const s16x4*)(pb);          // (y1, x)
                s16x4 B1 = *(const s16x4*)(pb + XSTR);   // (y1, x+1)
#pragma unroll
                for (int j = 0; j < 4; j++)
                    u.s8[hf * 4 + j] = f2bf(P.wa0 * h2f(A0[j]) + P.wb0 * h2f(A1[j]) +
                                            P.wa1 * h2f(B0[j]) + P.wb1 * h2f(B1[j]));
            }
            if (__builtin_expect(!P.in, 0)) {   // rare per-lane f32 recompute
#pragma unroll
                for (int j = 0; j < 8; j++) {
                    int cch = h * 32 + quad * 8 + j;
                    const float* xc = xb + ((size_t)cch << 14);
                    f32x2u q0 = *(const f32x2u*)(xc + P.gx0);
                    f32x2u q1 = *(const f32x2u*)(xc + P.gx1);
                    u.s8[j] = f2bf(P.wa0 * q0.x + P.wb0 * q0.y +
                                   P.wa1 * q1.x + P.wb1 * q1.y);
                }
            }
#pragma unroll
            for (int mt = 0; mt < 4; mt++) {
                bf16x8 a = *(const bf16x8*)(atd + t * 4096 + h * 2048 + mt * 512 + l * 8);
                acc[mt] = __builtin_amdgcn_mfma_f32_16x16x32_bf16(a, u.v, acc[mt], 0, 0, 0);
            }
        }
    }

    // Epilogue: D[row=quad*4+reg][col=lm]; o = mt*16+row, pixel = (ho, wo)
#pragma unroll
    for (int mt = 0; mt < 4; mt++) {
        float* op = out + ((size_t)(b * Oo + mt * 16 + quad * 4) << 14) + (ho << 7) + wo;
#pragma unroll
        for (int reg = 0; reg < 4; reg++)
            op[(size_t)reg << 14] = acc[mt][reg];
    }
}

// ---------------------------------------------------------------------------
extern "C" void kernel_launch(void* const* d_in, const int* in_sizes, int n_in,
                              void* d_out, int out_size, void* d_ws, size_t ws_size,
                              hipStream_t stream) {
    const float* x     = (const float*)d_in[0];
    const float* guide = (const float*)d_in[1];
    const float* w_off = (const float*)d_in[2];
    const float* b_off = (const float*)d_in[3];
    const float* w_mod = (const float*)d_in[4];
    const float* b_mod = (const float*)d_in[5];
    const float* w_reg = (const float*)d_in[6];
    float* out = (float*)d_out;
    float* ws  = (float*)d_ws;

    hipLaunchKernelGGL(prep_weights, dim3((73728 + 255) / 256), dim3(256),
                       0, stream, w_off, w_mod, w_reg, ws);
    hipLaunchKernelGGL(fused_dcn, dim3(Ww / 16, Hh / 4, Bn), dim3(256),
                       0, stream, x, guide, ws, b_off, b_mod, out);
}